// Round 6
// baseline (163.772 us; speedup 1.0000x reference)
//
#include <hip/hip_runtime.h>
#include <math.h>

// Marching tets, fully analytic grid. R15: SINGLE fused kernel (k_all) with
// block-offset software pipelining.
//  - Motivation: k_vert+k_face each ~30us (below the 43.6us harness-fill
//    visibility floor, no counters for 5 rounds) vs ~12us roofline; the
//    kernel boundary serializes two phases whose true data dependency spans
//    only ~50 vertex-blocks. Fuse: block b = vert-work for vertex-block b,
//    then face-work for cube-block fb = b - FOFF, FOFF = nb - nbC (=49).
//  - Dependency proof (R=64): face-block fb's max corner vertex =
//    256*fb + 255 + 8190(v(c)-c max) + 4291(corner offset) = 256*fb+12736
//    => vbHi = fb+49 = b. All rankWord/cubeInfo waits are BACKWARD-OR-SELF.
//  - Totals (M,N1): last block publishes one tag-protected word (totalsF);
//    face blocks poll it once. Only forward wait in the kernel.
//  - Deadlock safety: forward wait resolves iff all nb blocks dispatch;
//    needs nb-1024=49 retirements; blocks 0..FOFF-1 (=49) have no face
//    phase and only backward waits => retire => exact cover. REQUIRES 1024
//    resident slots: __launch_bounds__(256,4) (VGPR<=128) + 36.9KB LDS
//    (<=40KB => 4 blocks/CU). In-order dispatch already load-bearing (R13).
//  - Cross-XCD visibility: __syncthreads drains all waves' stores ->
//    thread0 RELEASE store flagF[b] (emits wbl2) -> readers spin relaxed,
//    __syncthreads, block-wide ACQUIRE fence (buffer_inv) -> plain cached
//    corner reads are fresh.
// Kept lessons: chain-free predecessor-sum scan (R13); cube-per-thread face
// decode with 8-corner rankWord reuse + cndmask sel8 (R13); LDS-staged dense
// copy-out for verts and faces (R11; scatter stores ~43 line-req/instr);
// compile-time c_dtab in __constant__ + magic-mul div + full unroll (R14);
// packed rankWord (R7); poison-safe tags: 0xAA.. (tag 10) and 0x00 (tag 00)
// both read not-ready (R8); fast tanh via v_exp_f32 (R9); no cooperative
// grid.sync (~100us, R6).

typedef unsigned long long ull;

#define ST_LD(p)    __hip_atomic_load((p), __ATOMIC_RELAXED, __HIP_MEMORY_SCOPE_AGENT)
#define ST_ST(p,v)  __hip_atomic_store((p), (v), __ATOMIC_RELAXED, __HIP_MEMORY_SCOPE_AGENT)

__device__ __forceinline__ float fast_tanh(float x) {
    float e = __expf(2.0f * x);                 // v_exp_f32 path
    return __fdividef(e - 1.0f, e + 1.0f);      // fast divide
}

// exact unsigned division by runtime constant d: M = ceil(2^46/d), host-side.
// Exact for v < 2^20, d < 2^13 (Granlund-Montgomery: e*N < 2^33 < 2^46).
__device__ __forceinline__ int divq(unsigned v, ull M) {
    return (int)(((ull)v * M) >> 46);
}

// ---- compile-time tables --------------------------------------------------
constexpr int TT[16][6] = {
    {-1,-1,-1,-1,-1,-1},{1,0,2,-1,-1,-1},{4,0,3,-1,-1,-1},{1,4,2,1,3,4},
    {3,1,5,-1,-1,-1},{2,3,0,2,5,3},{1,4,0,1,5,4},{4,2,5,-1,-1,-1},
    {4,5,2,-1,-1,-1},{4,1,0,4,5,1},{3,2,0,3,5,2},{1,3,5,-1,-1,-1},
    {4,1,2,4,3,1},{3,0,4,-1,-1,-1},{2,0,1,-1,-1,-1},{-1,-1,-1,-1,-1,-1}};
constexpr int NTRI[16] = {0,1,1,2,1,2,2,1,1,2,2,1,2,1,1,0};
constexpr int TC[6][4] = {{0,1,3,7},{0,3,2,7},{0,2,6,7},{0,6,4,7},{0,4,5,7},{0,5,1,7}};
constexpr int TE[6][6] = {
    {(0<<3)|0,(0<<3)|2,(0<<3)|6,(1<<3)|1,(1<<3)|5,(3<<3)|3},
    {(0<<3)|2,(0<<3)|1,(0<<3)|6,(2<<3)|0,(3<<3)|3,(2<<3)|4},
    {(0<<3)|1,(0<<3)|5,(0<<3)|6,(2<<3)|3,(2<<3)|4,(6<<3)|0},
    {(0<<3)|5,(0<<3)|3,(0<<3)|6,(4<<3)|1,(6<<3)|0,(4<<3)|2},
    {(0<<3)|3,(0<<3)|4,(0<<3)|6,(4<<3)|0,(4<<3)|2,(5<<3)|1},
    {(0<<3)|4,(0<<3)|0,(0<<3)|6,(1<<3)|3,(5<<3)|1,(1<<3)|5}};

// dtab word: nt:2 | pre1:3 | pre2:3 | 6 x (corner<<3|slot):6b at bit 8+6e.
struct DTabT { ull w[2048]; };
constexpr DTabT make_dtab() {
    DTabT t{};
    for (int ob = 0; ob < 256; ob++) {
        for (int k = 0; k < 8; k++) {
            ull w = 0;
            if (k < 6) {
                int ti = ((ob >> TC[k][0]) & 1) | (((ob >> TC[k][1]) & 1) << 1)
                       | (((ob >> TC[k][2]) & 1) << 2) | (((ob >> TC[k][3]) & 1) << 3);
                int nt = NTRI[ti];
                int pre1 = 0, pre2 = 0;
                for (int kk = 0; kk < k; kk++) {
                    int tik = ((ob >> TC[kk][0]) & 1) | (((ob >> TC[kk][1]) & 1) << 1)
                            | (((ob >> TC[kk][2]) & 1) << 2) | (((ob >> TC[kk][3]) & 1) << 3);
                    pre1 += (NTRI[tik] == 1); pre2 += (NTRI[tik] == 2);
                }
                w = (ull)nt | ((ull)pre1 << 2) | ((ull)pre2 << 5);
                for (int e = 0; e < 6; e++) {
                    int le = TT[ti][e];
                    int ce = (le >= 0) ? TE[k][le] : 0;
                    w |= (ull)ce << (8 + 6 * e);
                }
            }
            t.w[ob * 8 + k] = w;
        }
    }
    return t;
}
__device__ __constant__ DTabT c_dtab = make_dtab();

// state/flag word tag: [63:62] = 01 => ready. Poison 0xAA.. = 10, zero = 00.
#define TAG      (1ull << 62)
#define PMASK    ((1ull << 60) - 1ull)
#define READY(s) (((s) >> 62) == 1ull)

// corner select from 8 registers via cndmask tree (no runtime-indexed array).
__device__ __forceinline__ unsigned sel8(int c, unsigned r0, unsigned r1_, unsigned r2,
                                         unsigned r3, unsigned r4, unsigned r5,
                                         unsigned r6, unsigned r7) {
    unsigned a01 = (c & 1) ? r1_ : r0;
    unsigned a23 = (c & 1) ? r3 : r2;
    unsigned a45 = (c & 1) ? r5 : r4;
    unsigned a67 = (c & 1) ? r7 : r6;
    unsigned lo = (c & 2) ? a23 : a01;
    unsigned hi = (c & 2) ? a67 : a45;
    return (c & 4) ? hi : lo;
}

__global__ __launch_bounds__(256, 4) void k_all(
        const float* __restrict__ level, const float* __restrict__ deform,
        int NV, int NC, int r1, float invR,
        ull Mrsq, ull Mr1, ull Mrr, ull MR, int FOFF,
        ull* __restrict__ stateA, ull* __restrict__ flagF, ull* __restrict__ totalsF,
        unsigned* __restrict__ rankWord, ull* __restrict__ cubeInfo,
        float* __restrict__ out) {
    __shared__ float ldsB[9216];            // A: verts (<=5376); B: faces (<=9216)
    __shared__ int wE[4], wT[4];
    __shared__ ull sPart[4];
    __shared__ unsigned sB1, sB2, sE1, sE2;
    __shared__ ull sTot;

    int b = blockIdx.x, tid = threadIdx.x;
    int v = b * 256 + tid;
    int R = r1 - 1, rsq = r1 * r1, rr = R * R;

    // ================= Phase A: vertex emission + scan ======================
    bool valid = v < NV;
    float la = valid ? level[v] : 0.f;
    bool occv = valid && (la > 0.f);

    int x = 0, y = 0, z = 0, flags = 0, n1 = 0, n2 = 0, cidx = 0, ob = 0;
    bool interior = false;
    float lb[7];
    if (valid) {
        x = divq((unsigned)v, Mrsq); int rem = v - x * rsq;
        y = divq((unsigned)rem, Mr1); z = rem - y * r1;
        bool bx = x < R, by = y < R, bz = z < R;
        interior = bx && by && bz;
        bool inb[7] = {bz, by, by && bz, bx, bx && bz, bx && by, interior};
        int deltas[7] = {1, r1, r1 + 1, rsq, rsq + 1, rsq + r1, rsq + r1 + 1};
        ob = occv ? 1 : 0;
        #pragma unroll
        for (int j = 0; j < 7; j++) {
            float l = inb[j] ? level[v + deltas[j]] : 0.f;
            lb[j] = l;
            bool o = inb[j] && (l > 0.f);
            ob |= (o ? 1 : 0) << (j + 1);
            if (inb[j] && (o != occv)) flags |= 1 << j;
        }
        if (interior) {
            cidx = ((x * R) + y) * R + z;
            #pragma unroll
            for (int k = 0; k < 6; k++) {
                int ti = ((ob >> TC[k][0]) & 1) | (((ob >> TC[k][1]) & 1) << 1)
                       | (((ob >> TC[k][2]) & 1) << 2) | (((ob >> TC[k][3]) & 1) << 3);
                int p = __popc(ti);               // popc 1/3 -> 1 tri, 2 -> 2
                n1 += (p == 1) || (p == 3);
                n2 += (p == 2);
            }
        }
    }
    int cnt = __popc(flags);
    int pk = n1 | (n2 << 16);
    int lane = tid & 63, wv = tid >> 6;
    int inclE = cnt, inclT = pk;
    #pragma unroll
    for (int o = 1; o < 64; o <<= 1) {
        int tE = __shfl_up(inclE, o);
        int tT = __shfl_up(inclT, o);
        if (lane >= o) { inclE += tE; inclT += tT; }
    }
    if (lane == 63) { wE[wv] = inclE; wT[wv] = inclT; }
    __syncthreads();                                                    // S1

    // publish own aggregate early
    if (tid == 0) {
        int eb = wE[0] + wE[1] + wE[2] + wE[3];
        int tb = wT[0] + wT[1] + wT[2] + wT[3];
        ST_ST(&stateA[b], TAG | ((ull)eb << 40) | ((ull)(tb & 0xffff) << 20) | (ull)(tb >> 16));
    }
    int woffE = 0, woffT = 0;
    for (int w2 = 0; w2 < wv; w2++) { woffE += wE[w2]; woffT += wT[w2]; }
    int localRank = woffE + inclE - cnt;
    int tExcl = woffT + inclT - pk;

    // emission at LOCAL rank into LDS, overlapping predecessors' publication
    if (flags) {
        int deltas[7] = {1, r1, r1 + 1, rsq, rsq + 1, rsq + r1, rsq + r1 + 1};
        const int dxs[7] = {0, 0, 0, 1, 1, 1, 1};
        const int dys[7] = {0, 1, 1, 0, 0, 1, 1};
        const int dzs[7] = {1, 0, 1, 0, 1, 0, 1};
        float pax = x * invR + fast_tanh(deform[3 * v])     * invR;
        float pay = y * invR + fast_tanh(deform[3 * v + 1]) * invR;
        float paz = z * invR + fast_tanh(deform[3 * v + 2]) * invR;
        int r = localRank;
        #pragma unroll
        for (int j = 0; j < 7; j++) {
            if ((flags >> j) & 1) {
                int bb = v + deltas[j];
                float lbv = lb[j];
                float inv = __fdividef(1.0f, la - lbv);
                float w0 = -lbv * inv;
                float w1f = la * inv;
                float pbx = (x + dxs[j]) * invR + fast_tanh(deform[3 * bb])     * invR;
                float pby = (y + dys[j]) * invR + fast_tanh(deform[3 * bb + 1]) * invR;
                float pbz = (z + dzs[j]) * invR + fast_tanh(deform[3 * bb + 2]) * invR;
                ldsB[3 * r]     = pax * w0 + pbx * w1f;
                ldsB[3 * r + 1] = pay * w0 + pby * w1f;
                ldsB[3 * r + 2] = paz * w0 + pbz * w1f;
                r++;
            }
        }
    }

    // chain-free predecessor spin (backward-only); 4 waves take chunks 4t+wv
    ull psum = 0;
    for (int t = 0;; t++) {
        int base = 64 * (4 * t + wv);
        if (base >= b) break;                  // wave-uniform exit
        int i = b - 1 - (base + lane);
        ull s = 0;
        if (i >= 0) {
            do { s = ST_LD(&stateA[i]); } while (!READY(s));
            s &= PMASK;
        }
        psum += s;
    }
    #pragma unroll
    for (int o = 1; o < 64; o <<= 1) psum += __shfl_xor(psum, o);
    if (lane == 0) sPart[wv] = psum;
    __syncthreads();                                                    // S2

    ull ex = sPart[0] + sPart[1] + sPart[2] + sPart[3];
    int exclE = (int)((ex >> 40) & 0xFFFFF);
    int excl1 = (int)((ex >> 20) & 0xFFFFF);
    int excl2 = (int)(ex & 0xFFFFF);
    int eb2 = wE[0] + wE[1] + wE[2] + wE[3];
    if (tid == 0 && b == (int)gridDim.x - 1) {
        int tb = wT[0] + wT[1] + wT[2] + wT[3];
        ull inc = ex + (((ull)eb2 << 40) | ((ull)(tb & 0xffff) << 20) | (ull)(tb >> 16));
        ST_ST(totalsF, TAG | inc);             // single grand-total word
    }
    if (interior)
        cubeInfo[cidx] = (ull)(unsigned)ob
                       | ((ull)(unsigned)(excl1 + (tExcl & 0xffff)) << 8)
                       | ((ull)(unsigned)(excl2 + (tExcl >> 16)) << 28);
    if (valid)
        rankWord[v] = (unsigned)(exclE + localRank) | ((unsigned)flags << 21);

    __syncthreads();      // S3: drains every wave's stores (vmcnt) pre-flag
    if (tid == 0)         // release: wbl2 flushes this XCD's L2, then flag
        __hip_atomic_store(&flagF[b], TAG | 1ull, __ATOMIC_RELEASE, __HIP_MEMORY_SCOPE_AGENT);

    // dense coalesced vert copy-out
    {
        int tot = 3 * eb2;
        float* dstV = out + 3 * (size_t)exclE;
        for (int i = tid; i < tot; i += 256) dstV[i] = ldsB[i];
    }
    __syncthreads();      // S4: protect ldsB before phase B reuses it

    // ================= Phase B: face decode for cube-block b-FOFF ===========
    int fb = b - FOFF;
    if (fb >= 0) {
        int c = fb * 256 + tid;
        bool act = c < NC;

        // wait for publication of the needed vertex-block span (all <= b)
        int c0 = fb * 256;
        int c1e = c0 + 255; if (c1e > NC - 1) c1e = NC - 1;
        int cx0 = divq((unsigned)c0, Mrr); int rem0 = c0 - cx0 * rr;
        int cy0 = divq((unsigned)rem0, MR);
        int vlo = (cx0 * r1 + cy0) * r1 + (rem0 - cy0 * R);
        int cx1 = divq((unsigned)c1e, Mrr); int rem1 = c1e - cx1 * rr;
        int cy1 = divq((unsigned)rem1, MR);
        int vhi = (cx1 * r1 + cy1) * r1 + (rem1 - cy1 * R) + rsq + r1 + 1;
        int vbLo = vlo >> 8, vbHi = vhi >> 8;           // vbHi <= b by FOFF
        if (tid <= vbHi - vbLo) {
            ull f;
            do { f = ST_LD(&flagF[vbLo + tid]); } while (!READY(f));
        }
        __syncthreads();                                               // S5
        __builtin_amdgcn_fence(__ATOMIC_ACQUIRE, "agent");  // inv stale L1/L2

        ull info = 0;
        ull w0 = 0, w1 = 0, w2 = 0, w3 = 0, w4 = 0, w5 = 0;
        unsigned rw0=0,rw1=0,rw2=0,rw3=0,rw4=0,rw5=0,rw6=0,rw7=0;
        if (act) {
            info = cubeInfo[c];
            int obf = (int)info & 255;
            const ull* dp = &c_dtab.w[obf << 3];
            ulonglong2 p0 = *reinterpret_cast<const ulonglong2*>(dp);
            ulonglong2 p1 = *reinterpret_cast<const ulonglong2*>(dp + 2);
            ulonglong2 p2 = *reinterpret_cast<const ulonglong2*>(dp + 4);
            w0 = p0.x; w1 = p0.y; w2 = p1.x; w3 = p1.y; w4 = p2.x; w5 = p2.y;
            int cx = divq((unsigned)c, Mrr); int rem = c - cx * rr;
            int cy = divq((unsigned)rem, MR); int cz = rem - cy * R;
            int vc = (cx * r1 + cy) * r1 + cz;
            rw0 = rankWord[vc];             rw1 = rankWord[vc + 1];
            rw2 = rankWord[vc + r1];        rw3 = rankWord[vc + r1 + 1];
            rw4 = rankWord[vc + rsq];       rw5 = rankWord[vc + rsq + 1];
            rw6 = rankWord[vc + rsq + r1];  rw7 = rankWord[vc + rsq + r1 + 1];
        }
        unsigned r1c = (unsigned)((info >> 8) & 0xFFFFF);
        unsigned r2c = (unsigned)((info >> 28) & 0xFFFFF);
        int nt5 = (int)w5 & 3;
        int n1c = (((int)w5 >> 2) & 7) + (nt5 == 1);
        int n2c = (((int)w5 >> 5) & 7) + (nt5 == 2);

        int lastT = NC - 1 - fb * 256; if (lastT > 255) lastT = 255;
        if (tid == 0)     { sB1 = r1c; sB2 = r2c; }
        if (tid == lastT) { sE1 = r1c + (unsigned)n1c; sE2 = r2c + (unsigned)n2c; }
        __syncthreads();                                               // S6

        int n1b = (int)(sE1 - sB1), n2b = (int)(sE2 - sB2);
        float* Lr1 = ldsB;
        float* Lr2 = ldsB + 3 * n1b;

        #define ERANK(ce_)                                                      \
            ({ int ce = (ce_);                                                  \
               unsigned rw = sel8(ce >> 3, rw0,rw1,rw2,rw3,rw4,rw5,rw6,rw7);    \
               (float)((int)(rw & 0x1FFFFF) + __popc((rw >> 21) & ((1u << (ce & 7)) - 1u))); })

        if (act) {
            int local1 = (int)(r1c - sB1);
            int local2 = (int)(r2c - sB2);
            #define DO_TET(wk) do {                                             \
                int nt = (int)(wk) & 3;                                         \
                if (nt) {                                                       \
                    ull we = (wk) >> 8;                                         \
                    if (nt == 1) {                                              \
                        int s = local1 + (((int)(wk) >> 2) & 7);                \
                        float* d = &Lr1[3 * s];                                 \
                        d[0] = ERANK((int)(we) & 63);                           \
                        d[1] = ERANK((int)(we >> 6) & 63);                      \
                        d[2] = ERANK((int)(we >> 12) & 63);                     \
                    } else {                                                    \
                        int s = local2 + (((int)(wk) >> 5) & 7);                \
                        float* d = &Lr2[6 * s];                                 \
                        d[0] = ERANK((int)(we) & 63);                           \
                        d[1] = ERANK((int)(we >> 6) & 63);                      \
                        d[2] = ERANK((int)(we >> 12) & 63);                     \
                        d[3] = ERANK((int)(we >> 18) & 63);                     \
                        d[4] = ERANK((int)(we >> 24) & 63);                     \
                        d[5] = ERANK((int)(we >> 30) & 63);                     \
                    }                                                           \
                }                                                               \
            } while (0)
            DO_TET(w0); DO_TET(w1); DO_TET(w2); DO_TET(w3); DO_TET(w4); DO_TET(w5);
            #undef DO_TET
        }
        #undef ERANK

        // grand totals: poll the single word published by the last block
        if (tid == 0) {
            ull t;
            do { t = ST_LD(totalsF); } while (!READY(t));
            sTot = t;
        }
        __syncthreads();                                               // S7

        ull tot = sTot;
        int M  = (int)((tot >> 40) & 0xFFFFF);
        int N1 = (int)((tot >> 20) & 0xFFFFF);
        float* faces = out + 3 * (size_t)M;
        float* d1 = faces + 3 * (size_t)sB1;
        for (int i = tid; i < 3 * n1b; i += 256) d1[i] = ldsB[i];
        float* d2 = faces + 3 * (size_t)N1 + 6 * (size_t)sB2;
        const float* s2 = ldsB + 3 * n1b;
        for (int i = tid; i < 6 * n2b; i += 256) d2[i] = s2[i];
    }
}

extern "C" void kernel_launch(void* const* d_in, const int* in_sizes, int n_in,
                              void* d_out, int out_size, void* d_ws, size_t ws_size,
                              hipStream_t stream) {
    const float* level  = (const float*)d_in[0];
    const float* deform = (const float*)d_in[1];
    int NV = in_sizes[0];
    int r1 = 1;
    while ((long long)r1 * r1 * r1 < (long long)NV) r1++;
    int R = r1 - 1;
    float invR = 1.0f / (float)R;
    int rsq = r1 * r1, rr = R * R;

    // exact-division magics: M = ceil(2^46/d)
    ull Mrsq = ((1ull << 46) + (ull)rsq - 1) / (ull)rsq;
    ull Mr1  = ((1ull << 46) + (ull)r1  - 1) / (ull)r1;
    ull Mrr  = ((1ull << 46) + (ull)rr  - 1) / (ull)rr;
    ull MR   = ((1ull << 46) + (ull)R   - 1) / (ull)R;

    int nb = (NV + 255) / 256;
    int NC = R * R * R;
    int nbC = (NC + 255) / 256;
    int FOFF = nb - nbC;   // =49 at R=64; face waits become backward-or-self

    char* w = (char*)d_ws;
    unsigned* rankWord = (unsigned*)w;
    w += (((size_t)NV * sizeof(unsigned)) + 255) & ~(size_t)255;
    ull* cubeInfo = (ull*)w;
    w += (((size_t)NC * 8) + 255) & ~(size_t)255;
    ull* stateA = (ull*)w;
    w += (((size_t)nb * 8) + 255) & ~(size_t)255;
    ull* flagF = (ull*)w;
    w += (((size_t)nb * 8) + 255) & ~(size_t)255;
    ull* totalsF = (ull*)w;

    float* out = (float*)d_out;

    k_all<<<nb, 256, 0, stream>>>(level, deform, NV, NC, r1, invR,
                                  Mrsq, Mr1, Mrr, MR, FOFF,
                                  stateA, flagF, totalsF, rankWord, cubeInfo, out);
}

// Round 7
// 110.815 us; speedup vs baseline: 1.4779x; 1.4779x over previous
//
#include <hip/hip_runtime.h>
#include <math.h>

// Marching tets, fully analytic grid. R16: fused kernel, NO L2-wide cache
// maintenance.
//  - R15 diagnosis (first visible counters!): k_all 87us, VALU 14%, HBM 0.9%
//    => ~75us of collective stall. New-in-R15 suspects: per-block RELEASE
//    store (emits buffer_wbl2: full 4MB L2 writeback) + ACQUIRE fence
//    (buffer_inv: full L2 invalidate) ~1000x per dispatch => every XCD's
//    warm level/deform/rankWord lines repeatedly destroyed; loads degrade to
//    L3 latency chip-wide. (FETCH stays 6MB because L3 absorbs refills.)
//  - FIX: element-wise coherence instead of L2-wide: rankWord/cubeInfo are
//    written with relaxed AGENT atomic stores (write-through, no wbl2) and
//    read with relaxed AGENT atomic loads (coherence-point reads, no inv).
//    Flag ordering: S3 __syncthreads drains vmcnt(0) => data stores ACKED at
//    coherence point before the relaxed flag store issues (same mechanism the
//    R9-R14 stateA spins already validated cross-XCD). Acquire fence DELETED;
//    L2 stays warm for level/deform.
//  - All spin loops get s_sleep backoff (stateA/flagF: 1, totalsF park: 8)
//    to avoid fabric hammering by ~1000 concurrent pollers.
// Kept lessons: block-offset pipelining, FOFF = nb-nbC = 49, backward-or-self
// dependency proof + deadlock analysis (R15); chain-free predecessor-sum scan
// (R13); cube-per-thread face decode, 8-corner rankWord reuse + sel8 (R13);
// LDS-staged dense copy-out (R11); compile-time c_dtab + magic-mul div +
// full unroll (R14); packed rankWord (R7); poison-safe tags (R8); fast tanh
// via v_exp_f32 (R9); no cooperative grid.sync (R6).

typedef unsigned long long ull;

#define ST_LD(p)    __hip_atomic_load((p), __ATOMIC_RELAXED, __HIP_MEMORY_SCOPE_AGENT)
#define ST_ST(p,v)  __hip_atomic_store((p), (v), __ATOMIC_RELAXED, __HIP_MEMORY_SCOPE_AGENT)

__device__ __forceinline__ float fast_tanh(float x) {
    float e = __expf(2.0f * x);                 // v_exp_f32 path
    return __fdividef(e - 1.0f, e + 1.0f);      // fast divide
}

// exact unsigned division by runtime constant d: M = ceil(2^46/d), host-side.
// Exact for v < 2^20, d < 2^13 (Granlund-Montgomery: e*N < 2^33 < 2^46).
__device__ __forceinline__ int divq(unsigned v, ull M) {
    return (int)(((ull)v * M) >> 46);
}

// ---- compile-time tables --------------------------------------------------
constexpr int TT[16][6] = {
    {-1,-1,-1,-1,-1,-1},{1,0,2,-1,-1,-1},{4,0,3,-1,-1,-1},{1,4,2,1,3,4},
    {3,1,5,-1,-1,-1},{2,3,0,2,5,3},{1,4,0,1,5,4},{4,2,5,-1,-1,-1},
    {4,5,2,-1,-1,-1},{4,1,0,4,5,1},{3,2,0,3,5,2},{1,3,5,-1,-1,-1},
    {4,1,2,4,3,1},{3,0,4,-1,-1,-1},{2,0,1,-1,-1,-1},{-1,-1,-1,-1,-1,-1}};
constexpr int NTRI[16] = {0,1,1,2,1,2,2,1,1,2,2,1,2,1,1,0};
constexpr int TC[6][4] = {{0,1,3,7},{0,3,2,7},{0,2,6,7},{0,6,4,7},{0,4,5,7},{0,5,1,7}};
constexpr int TE[6][6] = {
    {(0<<3)|0,(0<<3)|2,(0<<3)|6,(1<<3)|1,(1<<3)|5,(3<<3)|3},
    {(0<<3)|2,(0<<3)|1,(0<<3)|6,(2<<3)|0,(3<<3)|3,(2<<3)|4},
    {(0<<3)|1,(0<<3)|5,(0<<3)|6,(2<<3)|3,(2<<3)|4,(6<<3)|0},
    {(0<<3)|5,(0<<3)|3,(0<<3)|6,(4<<3)|1,(6<<3)|0,(4<<3)|2},
    {(0<<3)|3,(0<<3)|4,(0<<3)|6,(4<<3)|0,(4<<3)|2,(5<<3)|1},
    {(0<<3)|4,(0<<3)|0,(0<<3)|6,(1<<3)|3,(5<<3)|1,(1<<3)|5}};

// dtab word: nt:2 | pre1:3 | pre2:3 | 6 x (corner<<3|slot):6b at bit 8+6e.
struct DTabT { ull w[2048]; };
constexpr DTabT make_dtab() {
    DTabT t{};
    for (int ob = 0; ob < 256; ob++) {
        for (int k = 0; k < 8; k++) {
            ull w = 0;
            if (k < 6) {
                int ti = ((ob >> TC[k][0]) & 1) | (((ob >> TC[k][1]) & 1) << 1)
                       | (((ob >> TC[k][2]) & 1) << 2) | (((ob >> TC[k][3]) & 1) << 3);
                int nt = NTRI[ti];
                int pre1 = 0, pre2 = 0;
                for (int kk = 0; kk < k; kk++) {
                    int tik = ((ob >> TC[kk][0]) & 1) | (((ob >> TC[kk][1]) & 1) << 1)
                            | (((ob >> TC[kk][2]) & 1) << 2) | (((ob >> TC[kk][3]) & 1) << 3);
                    pre1 += (NTRI[tik] == 1); pre2 += (NTRI[tik] == 2);
                }
                w = (ull)nt | ((ull)pre1 << 2) | ((ull)pre2 << 5);
                for (int e = 0; e < 6; e++) {
                    int le = TT[ti][e];
                    int ce = (le >= 0) ? TE[k][le] : 0;
                    w |= (ull)ce << (8 + 6 * e);
                }
            }
            t.w[ob * 8 + k] = w;
        }
    }
    return t;
}
__device__ __constant__ DTabT c_dtab = make_dtab();

// state/flag word tag: [63:62] = 01 => ready. Poison 0xAA.. = 10, zero = 00.
#define TAG      (1ull << 62)
#define PMASK    ((1ull << 60) - 1ull)
#define READY(s) (((s) >> 62) == 1ull)

// corner select from 8 registers via cndmask tree (no runtime-indexed array).
__device__ __forceinline__ unsigned sel8(int c, unsigned r0, unsigned r1_, unsigned r2,
                                         unsigned r3, unsigned r4, unsigned r5,
                                         unsigned r6, unsigned r7) {
    unsigned a01 = (c & 1) ? r1_ : r0;
    unsigned a23 = (c & 1) ? r3 : r2;
    unsigned a45 = (c & 1) ? r5 : r4;
    unsigned a67 = (c & 1) ? r7 : r6;
    unsigned lo = (c & 2) ? a23 : a01;
    unsigned hi = (c & 2) ? a67 : a45;
    return (c & 4) ? hi : lo;
}

__global__ __launch_bounds__(256, 4) void k_all(
        const float* __restrict__ level, const float* __restrict__ deform,
        int NV, int NC, int r1, float invR,
        ull Mrsq, ull Mr1, ull Mrr, ull MR, int FOFF,
        ull* __restrict__ stateA, ull* __restrict__ flagF, ull* __restrict__ totalsF,
        unsigned* __restrict__ rankWord, ull* __restrict__ cubeInfo,
        float* __restrict__ out) {
    __shared__ float ldsB[9216];            // A: verts (<=5376); B: faces (<=9216)
    __shared__ int wE[4], wT[4];
    __shared__ ull sPart[4];
    __shared__ unsigned sB1, sB2, sE1, sE2;
    __shared__ ull sTot;

    int b = blockIdx.x, tid = threadIdx.x;
    int v = b * 256 + tid;
    int R = r1 - 1, rsq = r1 * r1, rr = R * R;

    // ================= Phase A: vertex emission + scan ======================
    bool valid = v < NV;
    float la = valid ? level[v] : 0.f;
    bool occv = valid && (la > 0.f);

    int x = 0, y = 0, z = 0, flags = 0, n1 = 0, n2 = 0, cidx = 0, ob = 0;
    bool interior = false;
    float lb[7];
    if (valid) {
        x = divq((unsigned)v, Mrsq); int rem = v - x * rsq;
        y = divq((unsigned)rem, Mr1); z = rem - y * r1;
        bool bx = x < R, by = y < R, bz = z < R;
        interior = bx && by && bz;
        bool inb[7] = {bz, by, by && bz, bx, bx && bz, bx && by, interior};
        int deltas[7] = {1, r1, r1 + 1, rsq, rsq + 1, rsq + r1, rsq + r1 + 1};
        ob = occv ? 1 : 0;
        #pragma unroll
        for (int j = 0; j < 7; j++) {
            float l = inb[j] ? level[v + deltas[j]] : 0.f;
            lb[j] = l;
            bool o = inb[j] && (l > 0.f);
            ob |= (o ? 1 : 0) << (j + 1);
            if (inb[j] && (o != occv)) flags |= 1 << j;
        }
        if (interior) {
            cidx = ((x * R) + y) * R + z;
            #pragma unroll
            for (int k = 0; k < 6; k++) {
                int ti = ((ob >> TC[k][0]) & 1) | (((ob >> TC[k][1]) & 1) << 1)
                       | (((ob >> TC[k][2]) & 1) << 2) | (((ob >> TC[k][3]) & 1) << 3);
                int p = __popc(ti);               // popc 1/3 -> 1 tri, 2 -> 2
                n1 += (p == 1) || (p == 3);
                n2 += (p == 2);
            }
        }
    }
    int cnt = __popc(flags);
    int pk = n1 | (n2 << 16);
    int lane = tid & 63, wv = tid >> 6;
    int inclE = cnt, inclT = pk;
    #pragma unroll
    for (int o = 1; o < 64; o <<= 1) {
        int tE = __shfl_up(inclE, o);
        int tT = __shfl_up(inclT, o);
        if (lane >= o) { inclE += tE; inclT += tT; }
    }
    if (lane == 63) { wE[wv] = inclE; wT[wv] = inclT; }
    __syncthreads();                                                    // S1

    // publish own aggregate early
    if (tid == 0) {
        int eb = wE[0] + wE[1] + wE[2] + wE[3];
        int tb = wT[0] + wT[1] + wT[2] + wT[3];
        ST_ST(&stateA[b], TAG | ((ull)eb << 40) | ((ull)(tb & 0xffff) << 20) | (ull)(tb >> 16));
    }
    int woffE = 0, woffT = 0;
    for (int w2 = 0; w2 < wv; w2++) { woffE += wE[w2]; woffT += wT[w2]; }
    int localRank = woffE + inclE - cnt;
    int tExcl = woffT + inclT - pk;

    // emission at LOCAL rank into LDS, overlapping predecessors' publication
    if (flags) {
        int deltas[7] = {1, r1, r1 + 1, rsq, rsq + 1, rsq + r1, rsq + r1 + 1};
        const int dxs[7] = {0, 0, 0, 1, 1, 1, 1};
        const int dys[7] = {0, 1, 1, 0, 0, 1, 1};
        const int dzs[7] = {1, 0, 1, 0, 1, 0, 1};
        float pax = x * invR + fast_tanh(deform[3 * v])     * invR;
        float pay = y * invR + fast_tanh(deform[3 * v + 1]) * invR;
        float paz = z * invR + fast_tanh(deform[3 * v + 2]) * invR;
        int r = localRank;
        #pragma unroll
        for (int j = 0; j < 7; j++) {
            if ((flags >> j) & 1) {
                int bb = v + deltas[j];
                float lbv = lb[j];
                float inv = __fdividef(1.0f, la - lbv);
                float w0 = -lbv * inv;
                float w1f = la * inv;
                float pbx = (x + dxs[j]) * invR + fast_tanh(deform[3 * bb])     * invR;
                float pby = (y + dys[j]) * invR + fast_tanh(deform[3 * bb + 1]) * invR;
                float pbz = (z + dzs[j]) * invR + fast_tanh(deform[3 * bb + 2]) * invR;
                ldsB[3 * r]     = pax * w0 + pbx * w1f;
                ldsB[3 * r + 1] = pay * w0 + pby * w1f;
                ldsB[3 * r + 2] = paz * w0 + pbz * w1f;
                r++;
            }
        }
    }

    // chain-free predecessor spin (backward-only); 4 waves take chunks 4t+wv
    ull psum = 0;
    for (int t = 0;; t++) {
        int base = 64 * (4 * t + wv);
        if (base >= b) break;                  // wave-uniform exit
        int i = b - 1 - (base + lane);
        ull s = 0;
        if (i >= 0) {
            for (;;) {
                s = ST_LD(&stateA[i]);
                if (READY(s)) break;
                __builtin_amdgcn_s_sleep(1);
            }
            s &= PMASK;
        }
        psum += s;
    }
    #pragma unroll
    for (int o = 1; o < 64; o <<= 1) psum += __shfl_xor(psum, o);
    if (lane == 0) sPart[wv] = psum;
    __syncthreads();                                                    // S2

    ull ex = sPart[0] + sPart[1] + sPart[2] + sPart[3];
    int exclE = (int)((ex >> 40) & 0xFFFFF);
    int excl1 = (int)((ex >> 20) & 0xFFFFF);
    int excl2 = (int)(ex & 0xFFFFF);
    int eb2 = wE[0] + wE[1] + wE[2] + wE[3];
    if (tid == 0 && b == (int)gridDim.x - 1) {
        int tb = wT[0] + wT[1] + wT[2] + wT[3];
        ull inc = ex + (((ull)eb2 << 40) | ((ull)(tb & 0xffff) << 20) | (ull)(tb >> 16));
        ST_ST(totalsF, TAG | inc);             // single grand-total word
    }
    // cross-block intermediates: element-wise coherent stores (write-through,
    // NO buffer_wbl2). Readers use ST_LD => NO acquire fence / buffer_inv.
    if (interior)
        ST_ST(&cubeInfo[cidx],
              (ull)(unsigned)ob
            | ((ull)(unsigned)(excl1 + (tExcl & 0xffff)) << 8)
            | ((ull)(unsigned)(excl2 + (tExcl >> 16)) << 28));
    if (valid)
        ST_ST(&rankWord[v], (unsigned)(exclE + localRank) | ((unsigned)flags << 21));

    __syncthreads();      // S3: drains vmcnt(0) => data stores ACKED at
                          // coherence point before the flag store issues
    if (tid == 0)
        ST_ST(&flagF[b], TAG | 1ull);

    // dense coalesced vert copy-out
    {
        int tot = 3 * eb2;
        float* dstV = out + 3 * (size_t)exclE;
        for (int i = tid; i < tot; i += 256) dstV[i] = ldsB[i];
    }
    __syncthreads();      // S4: protect ldsB before phase B reuses it

    // ================= Phase B: face decode for cube-block b-FOFF ===========
    int fb = b - FOFF;
    if (fb >= 0) {
        int c = fb * 256 + tid;
        bool act = c < NC;

        // wait for publication of the needed vertex-block span (all <= b)
        int c0 = fb * 256;
        int c1e = c0 + 255; if (c1e > NC - 1) c1e = NC - 1;
        int cx0 = divq((unsigned)c0, Mrr); int rem0 = c0 - cx0 * rr;
        int cy0 = divq((unsigned)rem0, MR);
        int vlo = (cx0 * r1 + cy0) * r1 + (rem0 - cy0 * R);
        int cx1 = divq((unsigned)c1e, Mrr); int rem1 = c1e - cx1 * rr;
        int cy1 = divq((unsigned)rem1, MR);
        int vhi = (cx1 * r1 + cy1) * r1 + (rem1 - cy1 * R) + rsq + r1 + 1;
        int vbLo = vlo >> 8, vbHi = vhi >> 8;           // vbHi <= b by FOFF
        if (tid <= vbHi - vbLo) {
            for (;;) {
                ull f = ST_LD(&flagF[vbLo + tid]);
                if (READY(f)) break;
                __builtin_amdgcn_s_sleep(1);
            }
        }
        __syncthreads();                                               // S5

        ull info = 0;
        ull w0 = 0, w1 = 0, w2 = 0, w3 = 0, w4 = 0, w5 = 0;
        unsigned rw0=0,rw1=0,rw2=0,rw3=0,rw4=0,rw5=0,rw6=0,rw7=0;
        if (act) {
            info = ST_LD(&cubeInfo[c]);
            int obf = (int)info & 255;
            const ull* dp = &c_dtab.w[obf << 3];
            ulonglong2 p0 = *reinterpret_cast<const ulonglong2*>(dp);
            ulonglong2 p1 = *reinterpret_cast<const ulonglong2*>(dp + 2);
            ulonglong2 p2 = *reinterpret_cast<const ulonglong2*>(dp + 4);
            w0 = p0.x; w1 = p0.y; w2 = p1.x; w3 = p1.y; w4 = p2.x; w5 = p2.y;
            int cx = divq((unsigned)c, Mrr); int rem = c - cx * rr;
            int cy = divq((unsigned)rem, MR); int cz = rem - cy * R;
            int vc = (cx * r1 + cy) * r1 + cz;
            rw0 = ST_LD(&rankWord[vc]);             rw1 = ST_LD(&rankWord[vc + 1]);
            rw2 = ST_LD(&rankWord[vc + r1]);        rw3 = ST_LD(&rankWord[vc + r1 + 1]);
            rw4 = ST_LD(&rankWord[vc + rsq]);       rw5 = ST_LD(&rankWord[vc + rsq + 1]);
            rw6 = ST_LD(&rankWord[vc + rsq + r1]);  rw7 = ST_LD(&rankWord[vc + rsq + r1 + 1]);
        }
        unsigned r1c = (unsigned)((info >> 8) & 0xFFFFF);
        unsigned r2c = (unsigned)((info >> 28) & 0xFFFFF);
        int nt5 = (int)w5 & 3;
        int n1c = (((int)w5 >> 2) & 7) + (nt5 == 1);
        int n2c = (((int)w5 >> 5) & 7) + (nt5 == 2);

        int lastT = NC - 1 - fb * 256; if (lastT > 255) lastT = 255;
        if (tid == 0)     { sB1 = r1c; sB2 = r2c; }
        if (tid == lastT) { sE1 = r1c + (unsigned)n1c; sE2 = r2c + (unsigned)n2c; }
        __syncthreads();                                               // S6

        int n1b = (int)(sE1 - sB1), n2b = (int)(sE2 - sB2);
        float* Lr1 = ldsB;
        float* Lr2 = ldsB + 3 * n1b;

        #define ERANK(ce_)                                                      \
            ({ int ce = (ce_);                                                  \
               unsigned rw = sel8(ce >> 3, rw0,rw1,rw2,rw3,rw4,rw5,rw6,rw7);    \
               (float)((int)(rw & 0x1FFFFF) + __popc((rw >> 21) & ((1u << (ce & 7)) - 1u))); })

        if (act) {
            int local1 = (int)(r1c - sB1);
            int local2 = (int)(r2c - sB2);
            #define DO_TET(wk) do {                                             \
                int nt = (int)(wk) & 3;                                         \
                if (nt) {                                                       \
                    ull we = (wk) >> 8;                                         \
                    if (nt == 1) {                                              \
                        int s = local1 + (((int)(wk) >> 2) & 7);                \
                        float* d = &Lr1[3 * s];                                 \
                        d[0] = ERANK((int)(we) & 63);                           \
                        d[1] = ERANK((int)(we >> 6) & 63);                      \
                        d[2] = ERANK((int)(we >> 12) & 63);                     \
                    } else {                                                    \
                        int s = local2 + (((int)(wk) >> 5) & 7);                \
                        float* d = &Lr2[6 * s];                                 \
                        d[0] = ERANK((int)(we) & 63);                           \
                        d[1] = ERANK((int)(we >> 6) & 63);                      \
                        d[2] = ERANK((int)(we >> 12) & 63);                     \
                        d[3] = ERANK((int)(we >> 18) & 63);                     \
                        d[4] = ERANK((int)(we >> 24) & 63);                     \
                        d[5] = ERANK((int)(we >> 30) & 63);                     \
                    }                                                           \
                }                                                               \
            } while (0)
            DO_TET(w0); DO_TET(w1); DO_TET(w2); DO_TET(w3); DO_TET(w4); DO_TET(w5);
            #undef DO_TET
        }
        #undef ERANK

        // grand totals: park with backoff (published ~when last block passes S2)
        if (tid == 0) {
            ull t;
            for (;;) {
                t = ST_LD(totalsF);
                if (READY(t)) break;
                __builtin_amdgcn_s_sleep(8);
            }
            sTot = t;
        }
        __syncthreads();                                               // S7

        ull tot = sTot;
        int M  = (int)((tot >> 40) & 0xFFFFF);
        int N1 = (int)((tot >> 20) & 0xFFFFF);
        float* faces = out + 3 * (size_t)M;
        float* d1 = faces + 3 * (size_t)sB1;
        for (int i = tid; i < 3 * n1b; i += 256) d1[i] = ldsB[i];
        float* d2 = faces + 3 * (size_t)N1 + 6 * (size_t)sB2;
        const float* s2 = ldsB + 3 * n1b;
        for (int i = tid; i < 6 * n2b; i += 256) d2[i] = s2[i];
    }
}

extern "C" void kernel_launch(void* const* d_in, const int* in_sizes, int n_in,
                              void* d_out, int out_size, void* d_ws, size_t ws_size,
                              hipStream_t stream) {
    const float* level  = (const float*)d_in[0];
    const float* deform = (const float*)d_in[1];
    int NV = in_sizes[0];
    int r1 = 1;
    while ((long long)r1 * r1 * r1 < (long long)NV) r1++;
    int R = r1 - 1;
    float invR = 1.0f / (float)R;
    int rsq = r1 * r1, rr = R * R;

    // exact-division magics: M = ceil(2^46/d)
    ull Mrsq = ((1ull << 46) + (ull)rsq - 1) / (ull)rsq;
    ull Mr1  = ((1ull << 46) + (ull)r1  - 1) / (ull)r1;
    ull Mrr  = ((1ull << 46) + (ull)rr  - 1) / (ull)rr;
    ull MR   = ((1ull << 46) + (ull)R   - 1) / (ull)R;

    int nb = (NV + 255) / 256;
    int NC = R * R * R;
    int nbC = (NC + 255) / 256;
    int FOFF = nb - nbC;   // =49 at R=64; face waits become backward-or-self

    char* w = (char*)d_ws;
    unsigned* rankWord = (unsigned*)w;
    w += (((size_t)NV * sizeof(unsigned)) + 255) & ~(size_t)255;
    ull* cubeInfo = (ull*)w;
    w += (((size_t)NC * 8) + 255) & ~(size_t)255;
    ull* stateA = (ull*)w;
    w += (((size_t)nb * 8) + 255) & ~(size_t)255;
    ull* flagF = (ull*)w;
    w += (((size_t)nb * 8) + 255) & ~(size_t)255;
    ull* totalsF = (ull*)w;

    float* out = (float*)d_out;

    k_all<<<nb, 256, 0, stream>>>(level, deform, NV, NC, r1, invR,
                                  Mrsq, Mr1, Mrr, MR, FOFF,
                                  stateA, flagF, totalsF, rankWord, cubeInfo, out);
}